// Round 22
// baseline (3721.896 us; speedup 1.0000x reference)
//
#include <hip/hip_runtime.h>

typedef unsigned short u16;
typedef __attribute__((ext_vector_type(8))) short bf16x8;
typedef __attribute__((ext_vector_type(8))) unsigned short u16x8;
typedef __attribute__((ext_vector_type(4))) float f32x4;

__device__ __forceinline__ float zz_bf2f(u16 u) {
    unsigned v = ((unsigned)u) << 16;
    return __builtin_bit_cast(float, v);
}
__device__ __forceinline__ u16 zz_f2bf(float f) {
    unsigned u = __builtin_bit_cast(unsigned, f);
    u += 0x7fffu + ((u >> 16) & 1u);
    return (u16)(u >> 16);
}

__device__ __forceinline__ u16x8 zz_ld8c(const void* p, size_t idx, bool isf) {
    if (isf) {
        const float* fp = (const float*)p + idx;
        f32x4 v0 = *(const f32x4*)fp;
        f32x4 v1 = *(const f32x4*)(fp + 4);
        u16x8 o;
#pragma unroll
        for (int t = 0; t < 4; t++) {
            o[t] = zz_f2bf(v0[t]);
            o[4 + t] = zz_f2bf(v1[t]);
        }
        return o;
    }
    return *(const u16x8*)((const u16*)p + idx);
}

struct f8 { float v[8]; };
__device__ __forceinline__ f8 zz_ld8f(const void* p, size_t idx, bool isf) {
    f8 r;
    if (isf) {
        const float* fp = (const float*)p + idx;
        f32x4 a = *(const f32x4*)fp;
        f32x4 b = *(const f32x4*)(fp + 4);
#pragma unroll
        for (int t = 0; t < 4; t++) {
            r.v[t] = a[t];
            r.v[4 + t] = b[t];
        }
    } else {
        const u16* up = (const u16*)p + idx;
#pragma unroll
        for (int t = 0; t < 8; t++) r.v[t] = zz_bf2f(up[t]);
    }
    return r;
}

__device__ __forceinline__ bool zz_isf(const void* x) {
    const u16* xu = (const u16*)x;
    int cnt = 0;
    for (int i = 0; i < 64; i++) {
        float v = zz_bf2f(xu[i]);
        float a = fabsf(v);
        if (!(a <= 1e8f) || (v != 0.f && a < 1e-8f)) cnt++;
    }
    return cnt >= 16;
}

#define MFMA16(a, b, c) __builtin_amdgcn_mfma_f32_16x16x32_bf16((a), (b), (c), 0, 0, 0)

// ---------------- m92-style 128x128-tile GEMM core ----------------
__device__ __forceinline__ void zz_gemm128(const void* __restrict__ A, size_t aOff, bool a32,
                                           const void* __restrict__ B, size_t bOff, bool b32,
                                           int K, int lda, int ldb, int tm, int tn,
                                           u16* As, u16* Bs, f32x4 acc[4][4]) {
    const int tid = threadIdx.x;
    const int lane = tid & 63;
    const int wid = tid >> 6;
    const int wr = wid >> 1, wc = wid & 1;
    const int c15 = lane & 15, g4 = lane >> 4;

    const int rA = tid >> 2;
    const int cA = (tid & 3) << 3;
    const size_t iA0 = aOff + (size_t)(tm * 128 + rA) * lda + cA;
    const size_t iA1 = iA0 + (size_t)64 * lda;
    const size_t iB0 = bOff + (size_t)(tn * 128 + rA) * ldb + cA;
    const size_t iB1 = iB0 + (size_t)64 * ldb;
    u16* sA0 = As + rA * 32 + cA;
    u16* sA1 = sA0 + 64 * 32;
    u16* sB0 = Bs + rA * 32 + cA;
    u16* sB1 = sB0 + 64 * 32;

    for (int k0 = 0; k0 < K; k0 += 32) {
        u16x8 a0 = zz_ld8c(A, iA0 + k0, a32);
        u16x8 a1 = zz_ld8c(A, iA1 + k0, a32);
        u16x8 b0 = zz_ld8c(B, iB0 + k0, b32);
        u16x8 b1 = zz_ld8c(B, iB1 + k0, b32);
        __syncthreads();
        *(u16x8*)sA0 = a0;
        *(u16x8*)sA1 = a1;
        *(u16x8*)sB0 = b0;
        *(u16x8*)sB1 = b1;
        __syncthreads();
        bf16x8 af[4], bfr[4];
#pragma unroll
        for (int mf = 0; mf < 4; mf++)
            af[mf] = *(const bf16x8*)(As + (wr * 64 + mf * 16 + c15) * 32 + g4 * 8);
#pragma unroll
        for (int nf = 0; nf < 4; nf++)
            bfr[nf] = *(const bf16x8*)(Bs + (wc * 64 + nf * 16 + c15) * 32 + g4 * 8);
#pragma unroll
        for (int mf = 0; mf < 4; mf++)
#pragma unroll
            for (int nf = 0; nf < 4; nf++) acc[mf][nf] = MFMA16(af[mf], bfr[nf], acc[mf][nf]);
    }
}

// ---------------- projections, NB batches x 8 heads in one launch ----------------
__global__ __launch_bounds__(256) void zk21_proj(const void* __restrict__ x, int b0,
                                                 const void* __restrict__ Qw, const void* __restrict__ Kw,
                                                 const void* __restrict__ Pw,
                                                 u16* __restrict__ QZ, u16* __restrict__ KZ,
                                                 u16* __restrict__ Vt) {
    __shared__ u16 As[128 * 32];
    __shared__ u16 Bs[128 * 32];
    const bool isf = zz_isf(x);
    const size_t TD = (size_t)2048 * 512;
    const size_t WD = (size_t)512 * 512;
    const int lb = blockIdx.z;
    const int seg = blockIdx.y;
    const int part = seg >> 3;
    const int h = seg & 7;
    const int slot = lb * 8 + h;
    const size_t xOff = (size_t)(b0 + lb) * TD;
    const int bx = blockIdx.x;

    f32x4 acc[4][4];
    const f32x4 zf = {0.f, 0.f, 0.f, 0.f};
#pragma unroll
    for (int i = 0; i < 4; i++)
#pragma unroll
        for (int j = 0; j < 4; j++) acc[i][j] = zf;

    const int lane = threadIdx.x & 63;
    const int wid = threadIdx.x >> 6;
    const int wr = wid >> 1, wc = wid & 1;
    const int c15 = lane & 15, g4 = lane >> 4;

    if (part < 2) {
        const void* W = (part == 0) ? Qw : Kw;
        u16* C = ((part == 0) ? QZ : KZ) + (size_t)slot * TD;
        const int tm = bx >> 2, tn = bx & 3;  // 2048x512
        zz_gemm128(x, xOff, isf, W, (size_t)h * WD, isf, 512, 512, 512, tm, tn, As, Bs, acc);
#pragma unroll
        for (int mf = 0; mf < 4; mf++)
#pragma unroll
            for (int nf = 0; nf < 4; nf++) {
                const int row0 = tm * 128 + wr * 64 + mf * 16 + g4 * 4;
                const int col = tn * 128 + wc * 64 + nf * 16 + c15;
#pragma unroll
                for (int r = 0; r < 4; r++) C[(size_t)(row0 + r) * 512 + col] = zz_f2bf(acc[mf][nf][r]);
            }
    } else {
        u16* C = Vt + (size_t)slot * TD;
        const int tm = bx >> 4, tn = bx & 15;  // 512x2048
        zz_gemm128(Pw, (size_t)h * WD, isf, x, xOff, isf, 512, 512, 512, tm, tn, As, Bs, acc);
#pragma unroll
        for (int mf = 0; mf < 4; mf++)
#pragma unroll
            for (int nf = 0; nf < 4; nf++) {
                const int row0 = tm * 128 + wr * 64 + mf * 16 + g4 * 4;
                const int col = tn * 128 + wc * 64 + nf * 16 + c15;
#pragma unroll
                for (int r = 0; r < 4; r++) C[(size_t)(row0 + r) * 2048 + col] = zz_f2bf(acc[mf][nf][r]);
            }
    }
}

// ---------------- flash: 4 waves per q-tile; wave w owns D-quarter w ----------------
// Each wave duplicates QK^T + softmax for its 16 q-rows (global K reads, L2/L3-resident),
// accumulates only 8 of 32 V-column fragments -> o[8] (32 VGPR) -> ~3 waves/SIMD resident.
// No barriers; per-wave P bounce via private LDS slice (same-wave RAW = lgkmcnt).
__global__ __launch_bounds__(256) void zk21_flash(const u16* __restrict__ QZ, const u16* __restrict__ KZ,
                                                  const u16* __restrict__ Vt, u16* __restrict__ Oc) {
    __shared__ u16 Plds[4][16 * 32];
    const int tid = threadIdx.x;
    const int w = tid >> 6;            // 0..3 = D-quarter
    const int lane = tid & 63;
    const int c = lane & 15, g = lane >> 4;
    const int lb = blockIdx.z;
    const int h = blockIdx.y;
    const int slot = lb * 8 + h;
    const int q0 = (127 - blockIdx.x) * 16;  // reversed: longest first
    const int T = 2048;
    const size_t TD = (size_t)T * 512;
    const float SCL2 = 0.06375826722338107f;  // (1/sqrt(512)) * log2(e)

    bf16x8 qf[16];
    const u16* Qp = QZ + (size_t)slot * TD + (size_t)(q0 + c) * 512 + g * 8;
#pragma unroll
    for (int ks = 0; ks < 16; ks++) qf[ks] = *(const bf16x8*)(Qp + ks * 32);

    const f32x4 zf = {0.f, 0.f, 0.f, 0.f};
    f32x4 o[8];
#pragma unroll
    for (int nf = 0; nf < 8; nf++) o[nf] = zf;
    float mR[4], lR[4];
#pragma unroll
    for (int r = 0; r < 4; r++) { mR[r] = -1e30f; lR[r] = 0.f; }

    const u16* Kbase = KZ + (size_t)slot * TD;
    const u16* Vbase = Vt + (size_t)slot * TD + (size_t)(w * 128 + c) * T;  // D-quarter rows

    for (int s0 = 0; s0 < q0 + 16; s0 += 32) {
        f32x4 sa0 = zf, sa1 = zf;
        const u16* Kp0 = Kbase + (size_t)(s0 + c) * 512 + g * 8;
        const u16* Kp1 = Kp0 + 16 * 512;
#pragma unroll
        for (int ks = 0; ks < 16; ks++) {
            bf16x8 k0v = *(const bf16x8*)(Kp0 + ks * 32);
            bf16x8 k1v = *(const bf16x8*)(Kp1 + ks * 32);
            sa0 = MFMA16(qf[ks], k0v, sa0);
            sa1 = MFMA16(qf[ks], k1v, sa1);
        }
        float fac[4], p0[4], p1[4];
#pragma unroll
        for (int r = 0; r < 4; r++) {
            const int t = q0 + g * 4 + r;
            float v0 = (s0 + c <= t) ? sa0[r] * SCL2 : -INFINITY;
            float v1 = (s0 + 16 + c <= t) ? sa1[r] * SCL2 : -INFINITY;
            float rm = fmaxf(v0, v1);
#pragma unroll
            for (int d = 1; d < 16; d <<= 1) rm = fmaxf(rm, __shfl_xor(rm, d));
            const float mN = fmaxf(mR[r], rm);
            fac[r] = exp2f(mR[r] - mN);
            mR[r] = mN;
            p0[r] = exp2f(v0 - mN);
            p1[r] = exp2f(v1 - mN);
            float rs = p0[r] + p1[r];
#pragma unroll
            for (int d = 1; d < 16; d <<= 1) rs += __shfl_xor(rs, d);
            lR[r] = lR[r] * fac[r] + rs;
            Plds[w][(g * 4 + r) * 32 + c] = zz_f2bf(p0[r]);
            Plds[w][(g * 4 + r) * 32 + 16 + c] = zz_f2bf(p1[r]);
        }
        const f32x4 facv = {fac[0], fac[1], fac[2], fac[3]};
#pragma unroll
        for (int nf = 0; nf < 8; nf++) o[nf] *= facv;
        const bf16x8 pa = *(const bf16x8*)(&Plds[w][c * 32 + g * 8]);  // same-wave RAW
        const u16* Vp = Vbase + s0 + g * 8;
#pragma unroll
        for (int nf = 0; nf < 8; nf++) {
            bf16x8 vf = *(const bf16x8*)(Vp + (size_t)nf * 16 * T);
            o[nf] = MFMA16(pa, vf, o[nf]);
        }
    }

    const f32x4 inv = {1.f / lR[0], 1.f / lR[1], 1.f / lR[2], 1.f / lR[3]};
#pragma unroll
    for (int nf = 0; nf < 8; nf++) {
        f32x4 ov = o[nf] * inv;
        const int d = w * 128 + nf * 16 + c;
#pragma unroll
        for (int r = 0; r < 4; r++) {
            const int t = q0 + g * 4 + r;
            Oc[(size_t)(lb * 2048 + t) * 4096 + h * 512 + d] = zz_f2bf(ov[r]);
        }
    }
}

// ---------------- output projection: y[lb] = Oc[lb](2048x4096) @ Wo^T, fp32 ----------------
__global__ __launch_bounds__(256) void zk21_oproj(const u16* __restrict__ Oc, const void* __restrict__ Wo,
                                                  float* __restrict__ y, const void* __restrict__ x) {
    __shared__ u16 As[128 * 32];
    __shared__ u16 Bs[128 * 32];
    const bool isf = zz_isf(x);
    const int lb = blockIdx.y;
    const int bx = blockIdx.x;
    const int tm = bx >> 2, tn = bx & 3;

    f32x4 acc[4][4];
    const f32x4 zf = {0.f, 0.f, 0.f, 0.f};
#pragma unroll
    for (int i = 0; i < 4; i++)
#pragma unroll
        for (int j = 0; j < 4; j++) acc[i][j] = zf;

    zz_gemm128(Oc, (size_t)lb * 2048 * 4096, false, Wo, 0, isf, 4096, 4096, 4096, tm, tn, As, Bs, acc);

    const int lane = threadIdx.x & 63;
    const int wid = threadIdx.x >> 6;
    const int wr = wid >> 1, wc = wid & 1;
    const int c15 = lane & 15, g4 = lane >> 4;
    float* yb = y + (size_t)lb * 2048 * 512;
#pragma unroll
    for (int mf = 0; mf < 4; mf++)
#pragma unroll
        for (int nf = 0; nf < 4; nf++) {
            const int row0 = tm * 128 + wr * 64 + mf * 16 + g4 * 4;
            const int col = tn * 128 + wc * 64 + nf * 16 + c15;
#pragma unroll
            for (int r = 0; r < 4; r++) yb[(size_t)(row0 + r) * 512 + col] = acc[mf][nf][r];
        }
}

// ---------------- bias + residual + LN; fp32 out (bf16 fallback) ----------------
__global__ __launch_bounds__(256) void zk21_ln(const float* __restrict__ y, const void* __restrict__ x,
                                               int b0, const void* __restrict__ bo,
                                               const void* __restrict__ ga, const void* __restrict__ be,
                                               void* __restrict__ outbase) {
    const bool isf = zz_isf(x);
    const int lb = blockIdx.y;
    const int wid = threadIdx.x >> 6, lane = threadIdx.x & 63;
    const int row = blockIdx.x * 4 + wid;
    const size_t grow = (size_t)(b0 + lb) * 2048 + row;
    const int d0 = lane * 8;
    const float* yp = y + ((size_t)lb * 2048 + row) * 512 + d0;
    f32x4 a0 = *(const f32x4*)(yp);
    f32x4 a1 = *(const f32x4*)(yp + 4);
    f8 xv = zz_ld8f(x, grow * 512 + d0, isf);
    f8 bov = zz_ld8f(bo, d0, isf);
    float h[8];
#pragma unroll
    for (int j = 0; j < 4; j++) {
        h[j] = a0[j] + bov.v[j] + xv.v[j];
        h[4 + j] = a1[j] + bov.v[4 + j] + xv.v[4 + j];
    }
    float sum = 0.f, sq = 0.f;
#pragma unroll
    for (int j = 0; j < 8; j++) {
        sum += h[j];
        sq += h[j] * h[j];
    }
#pragma unroll
    for (int d = 1; d < 64; d <<= 1) {
        sum += __shfl_xor(sum, d);
        sq += __shfl_xor(sq, d);
    }
    const float mean = sum * (1.f / 512.f);
    const float var = sq * (1.f / 512.f) - mean * mean;
    const float rstd = rsqrtf(var + 1e-5f);
    f8 gv = zz_ld8f(ga, d0, isf);
    f8 bv = zz_ld8f(be, d0, isf);
    const size_t o = grow * 512 + d0;
    if (isf) {
        float* op = (float*)outbase + o;
#pragma unroll
        for (int j = 0; j < 8; j++) op[j] = (h[j] - mean) * rstd * gv.v[j] + bv.v[j];
    } else {
        u16* op = (u16*)outbase + o;
#pragma unroll
        for (int j = 0; j < 8; j++) op[j] = zz_f2bf((h[j] - mean) * rstd * gv.v[j] + bv.v[j]);
    }
}

__global__ __launch_bounds__(256) void zk21_band(float* __restrict__ out, float val) {
    const size_t gid = (size_t)blockIdx.x * 256 + threadIdx.x;
    float* p = out + gid * 8;
#pragma unroll
    for (int j = 0; j < 8; j++) p[j] = val;
}

extern "C" void kernel_launch(void* const* d_in, const int* in_sizes, int n_in, void* d_out,
                              int out_size, void* d_ws, size_t ws_size, hipStream_t stream) {
    if (n_in != 8 || in_sizes[0] != 4194304 || in_sizes[5] != 512) {
        zk21_band<<<dim3(2048), dim3(256), 0, stream>>>((float*)d_out, 16.0f);
        return;
    }
    const void* x = d_in[0];
    const void* Pw = d_in[1];
    const void* Qw = d_in[2];
    const void* Kw = d_in[3];
    const void* Wo = d_in[4];
    const void* bo = d_in[5];
    const void* ga = d_in[6];
    const void* be = d_in[7];

    const size_t TD = (size_t)2048 * 512;

    auto need = [&](int nb) -> size_t {
        return 512 + (size_t)nb * (3 * 8 * TD * 2 + (size_t)2048 * 4096 * 2 + TD * 4);
    };
    int NB = 1;
    if (ws_size >= need(4)) NB = 4;
    else if (ws_size >= need(2)) NB = 2;

    u16* QZ = (u16*)d_ws + 256;
    u16* KZ = QZ + (size_t)NB * 8 * TD;
    u16* Vt = KZ + (size_t)NB * 8 * TD;
    u16* Oc = Vt + (size_t)NB * 8 * TD;
    float* y = (float*)(Oc + (size_t)NB * 2048 * 4096);

    for (int b0 = 0; b0 < 4; b0 += NB) {
        zk21_proj<<<dim3(64, 24, NB), dim3(256), 0, stream>>>(x, b0, Qw, Kw, Pw, QZ, KZ, Vt);
        zk21_flash<<<dim3(128, 8, NB), dim3(256), 0, stream>>>(QZ, KZ, Vt, Oc);
        zk21_oproj<<<dim3(64, NB), dim3(256), 0, stream>>>(Oc, Wo, y, x);
        zk21_ln<<<dim3(512, NB), dim3(256), 0, stream>>>(y, x, b0, bo, ga, be, d_out);
    }
}

// Round 23
// 2359.566 us; speedup vs baseline: 1.5774x; 1.5774x over previous
//
#include <hip/hip_runtime.h>

typedef unsigned short u16;
typedef __attribute__((ext_vector_type(8))) short bf16x8;
typedef __attribute__((ext_vector_type(8))) unsigned short u16x8;
typedef __attribute__((ext_vector_type(4))) float f32x4;

__device__ __forceinline__ float zz_bf2f(u16 u) {
    unsigned v = ((unsigned)u) << 16;
    return __builtin_bit_cast(float, v);
}
__device__ __forceinline__ u16 zz_f2bf(float f) {
    unsigned u = __builtin_bit_cast(unsigned, f);
    u += 0x7fffu + ((u >> 16) & 1u);
    return (u16)(u >> 16);
}

__device__ __forceinline__ u16x8 zz_ld8c(const void* p, size_t idx, bool isf) {
    if (isf) {
        const float* fp = (const float*)p + idx;
        f32x4 v0 = *(const f32x4*)fp;
        f32x4 v1 = *(const f32x4*)(fp + 4);
        u16x8 o;
#pragma unroll
        for (int t = 0; t < 4; t++) {
            o[t] = zz_f2bf(v0[t]);
            o[4 + t] = zz_f2bf(v1[t]);
        }
        return o;
    }
    return *(const u16x8*)((const u16*)p + idx);
}

struct f8 { float v[8]; };
__device__ __forceinline__ f8 zz_ld8f(const void* p, size_t idx, bool isf) {
    f8 r;
    if (isf) {
        const float* fp = (const float*)p + idx;
        f32x4 a = *(const f32x4*)fp;
        f32x4 b = *(const f32x4*)(fp + 4);
#pragma unroll
        for (int t = 0; t < 4; t++) {
            r.v[t] = a[t];
            r.v[4 + t] = b[t];
        }
    } else {
        const u16* up = (const u16*)p + idx;
#pragma unroll
        for (int t = 0; t < 8; t++) r.v[t] = zz_bf2f(up[t]);
    }
    return r;
}

__device__ __forceinline__ bool zz_isf(const void* x) {
    const u16* xu = (const u16*)x;
    int cnt = 0;
    for (int i = 0; i < 64; i++) {
        float v = zz_bf2f(xu[i]);
        float a = fabsf(v);
        if (!(a <= 1e8f) || (v != 0.f && a < 1e-8f)) cnt++;
    }
    return cnt >= 16;
}

#define MFMA16(a, b, c) __builtin_amdgcn_mfma_f32_16x16x32_bf16((a), (b), (c), 0, 0, 0)

// ---------------- m92-style 128x128-tile GEMM core ----------------
__device__ __forceinline__ void zz_gemm128(const void* __restrict__ A, size_t aOff, bool a32,
                                           const void* __restrict__ B, size_t bOff, bool b32,
                                           int K, int lda, int ldb, int tm, int tn,
                                           u16* As, u16* Bs, f32x4 acc[4][4]) {
    const int tid = threadIdx.x;
    const int lane = tid & 63;
    const int wid = tid >> 6;
    const int wr = wid >> 1, wc = wid & 1;
    const int c15 = lane & 15, g4 = lane >> 4;

    const int rA = tid >> 2;
    const int cA = (tid & 3) << 3;
    const size_t iA0 = aOff + (size_t)(tm * 128 + rA) * lda + cA;
    const size_t iA1 = iA0 + (size_t)64 * lda;
    const size_t iB0 = bOff + (size_t)(tn * 128 + rA) * ldb + cA;
    const size_t iB1 = iB0 + (size_t)64 * ldb;
    u16* sA0 = As + rA * 32 + cA;
    u16* sA1 = sA0 + 64 * 32;
    u16* sB0 = Bs + rA * 32 + cA;
    u16* sB1 = sB0 + 64 * 32;

    for (int k0 = 0; k0 < K; k0 += 32) {
        u16x8 a0 = zz_ld8c(A, iA0 + k0, a32);
        u16x8 a1 = zz_ld8c(A, iA1 + k0, a32);
        u16x8 b0 = zz_ld8c(B, iB0 + k0, b32);
        u16x8 b1 = zz_ld8c(B, iB1 + k0, b32);
        __syncthreads();
        *(u16x8*)sA0 = a0;
        *(u16x8*)sA1 = a1;
        *(u16x8*)sB0 = b0;
        *(u16x8*)sB1 = b1;
        __syncthreads();
        bf16x8 af[4], bfr[4];
#pragma unroll
        for (int mf = 0; mf < 4; mf++)
            af[mf] = *(const bf16x8*)(As + (wr * 64 + mf * 16 + c15) * 32 + g4 * 8);
#pragma unroll
        for (int nf = 0; nf < 4; nf++)
            bfr[nf] = *(const bf16x8*)(Bs + (wc * 64 + nf * 16 + c15) * 32 + g4 * 8);
#pragma unroll
        for (int mf = 0; mf < 4; mf++)
#pragma unroll
            for (int nf = 0; nf < 4; nf++) acc[mf][nf] = MFMA16(af[mf], bfr[nf], acc[mf][nf]);
    }
}

// ---------------- projections, NB batches x 8 heads in one launch ----------------
__global__ __launch_bounds__(256) void zk22_proj(const void* __restrict__ x, int b0,
                                                 const void* __restrict__ Qw, const void* __restrict__ Kw,
                                                 const void* __restrict__ Pw,
                                                 u16* __restrict__ QZ, u16* __restrict__ KZ,
                                                 u16* __restrict__ Vt) {
    __shared__ u16 As[128 * 32];
    __shared__ u16 Bs[128 * 32];
    const bool isf = zz_isf(x);
    const size_t TD = (size_t)2048 * 512;
    const size_t WD = (size_t)512 * 512;
    const int lb = blockIdx.z;
    const int seg = blockIdx.y;
    const int part = seg >> 3;
    const int h = seg & 7;
    const int slot = lb * 8 + h;
    const size_t xOff = (size_t)(b0 + lb) * TD;
    const int bx = blockIdx.x;

    f32x4 acc[4][4];
    const f32x4 zf = {0.f, 0.f, 0.f, 0.f};
#pragma unroll
    for (int i = 0; i < 4; i++)
#pragma unroll
        for (int j = 0; j < 4; j++) acc[i][j] = zf;

    const int lane = threadIdx.x & 63;
    const int wid = threadIdx.x >> 6;
    const int wr = wid >> 1, wc = wid & 1;
    const int c15 = lane & 15, g4 = lane >> 4;

    if (part < 2) {
        const void* W = (part == 0) ? Qw : Kw;
        u16* C = ((part == 0) ? QZ : KZ) + (size_t)slot * TD;
        const int tm = bx >> 2, tn = bx & 3;  // 2048x512
        zz_gemm128(x, xOff, isf, W, (size_t)h * WD, isf, 512, 512, 512, tm, tn, As, Bs, acc);
#pragma unroll
        for (int mf = 0; mf < 4; mf++)
#pragma unroll
            for (int nf = 0; nf < 4; nf++) {
                const int row0 = tm * 128 + wr * 64 + mf * 16 + g4 * 4;
                const int col = tn * 128 + wc * 64 + nf * 16 + c15;
#pragma unroll
                for (int r = 0; r < 4; r++) C[(size_t)(row0 + r) * 512 + col] = zz_f2bf(acc[mf][nf][r]);
            }
    } else {
        u16* C = Vt + (size_t)slot * TD;
        const int tm = bx >> 4, tn = bx & 15;  // 512x2048
        zz_gemm128(Pw, (size_t)h * WD, isf, x, xOff, isf, 512, 512, 512, tm, tn, As, Bs, acc);
#pragma unroll
        for (int mf = 0; mf < 4; mf++)
#pragma unroll
            for (int nf = 0; nf < 4; nf++) {
                const int row0 = tm * 128 + wr * 64 + mf * 16 + g4 * 4;
                const int col = tn * 128 + wc * 64 + nf * 16 + c15;
#pragma unroll
                for (int r = 0; r < 4; r++) C[(size_t)(row0 + r) * 2048 + col] = zz_f2bf(acc[mf][nf][r]);
            }
    }
}

// ---------------- flash v22: 1 wave = 16 q-rows, 64 keys/iter, XCD head affinity ----------------
// head = blockIdx.x & 7  -> blocks of head h land on XCD h (round-robin dispatch), so the
// 2MB K + 2MB V slot stays L2-resident per XCD. 4 independent QK chains (J=0..3).
// P bounce XOR-swizzled: col ^ ((row&7)<<3) -> conflict-free b128 reads.
__global__ __launch_bounds__(64) void zk22_flash(const u16* __restrict__ QZ, const u16* __restrict__ KZ,
                                                 const u16* __restrict__ Vt, u16* __restrict__ Oc) {
    __shared__ u16 Plds[16 * 64];
    const int lane = threadIdx.x & 63;
    const int c = lane & 15, g = lane >> 4;
    const int lb = blockIdx.z;
    const int h = blockIdx.x & 7;             // XCD affinity
    const int q0 = (127 - (blockIdx.x >> 3)) * 16;  // reversed: longest first
    const int slot = lb * 8 + h;
    const int T = 2048;
    const size_t TD = (size_t)T * 512;
    const float SCL2 = 0.06375826722338107f;  // (1/sqrt(512)) * log2(e)

    bf16x8 qf[16];
    const u16* Qp = QZ + (size_t)slot * TD + (size_t)(q0 + c) * 512 + g * 8;
#pragma unroll
    for (int ks = 0; ks < 16; ks++) qf[ks] = *(const bf16x8*)(Qp + ks * 32);

    const f32x4 zf = {0.f, 0.f, 0.f, 0.f};
    f32x4 o[32];
#pragma unroll
    for (int nf = 0; nf < 32; nf++) o[nf] = zf;
    float mR[4], lR[4];
#pragma unroll
    for (int r = 0; r < 4; r++) { mR[r] = -1e30f; lR[r] = 0.f; }

    const u16* Kbase = KZ + (size_t)slot * TD;
    const u16* Vbase = Vt + (size_t)slot * TD + (size_t)c * T;
    const int swc = (c & 7) << 3;

    for (int s0 = 0; s0 < q0 + 16; s0 += 64) {
        const int rem = q0 + 16 - s0;
        const int nJ = (rem >= 64) ? 4 : ((rem + 15) >> 4);  // live 16-key blocks (uniform)

        f32x4 sa[4] = {zf, zf, zf, zf};
#pragma unroll
        for (int ks = 0; ks < 16; ks++) {
#pragma unroll
            for (int J = 0; J < 4; J++) {
                if (J < nJ) {
                    bf16x8 kv = *(const bf16x8*)(Kbase + (size_t)(s0 + J * 16 + c) * 512 + ks * 32 + g * 8);
                    sa[J] = MFMA16(qf[ks], kv, sa[J]);
                }
            }
        }

        float fac[4];
#pragma unroll
        for (int r = 0; r < 4; r++) {
            const int t = q0 + g * 4 + r;
            const int row = g * 4 + r;
            const int sw = (row & 7) << 3;
            float v[4], p[4];
#pragma unroll
            for (int J = 0; J < 4; J++)
                v[J] = (J < nJ && s0 + J * 16 + c <= t) ? sa[J][r] * SCL2 : -INFINITY;
            float rm = fmaxf(fmaxf(v[0], v[1]), fmaxf(v[2], v[3]));
#pragma unroll
            for (int d = 1; d < 16; d <<= 1) rm = fmaxf(rm, __shfl_xor(rm, d));
            const float mN = fmaxf(mR[r], rm);
            fac[r] = exp2f(mR[r] - mN);
            mR[r] = mN;
            float rs = 0.f;
#pragma unroll
            for (int J = 0; J < 4; J++) {
                p[J] = exp2f(v[J] - mN);
                rs += p[J];
            }
#pragma unroll
            for (int d = 1; d < 16; d <<= 1) rs += __shfl_xor(rs, d);
            lR[r] = lR[r] * fac[r] + rs;
#pragma unroll
            for (int J = 0; J < 4; J++) Plds[row * 64 + ((J * 16 + c) ^ sw)] = zz_f2bf(p[J]);
        }
        const f32x4 facv = {fac[0], fac[1], fac[2], fac[3]};
#pragma unroll
        for (int nf = 0; nf < 32; nf++) o[nf] *= facv;

        // same-wave RAW on Plds -> compiler lgkmcnt
        const bf16x8 pa0 = *(const bf16x8*)(&Plds[c * 64 + ((g * 8) ^ swc)]);
        const bf16x8 pa1 = *(const bf16x8*)(&Plds[c * 64 + ((32 + g * 8) ^ swc)]);
        const u16* Vp = Vbase + s0 + g * 8;
#pragma unroll
        for (int nf = 0; nf < 32; nf++) {
            bf16x8 vf = *(const bf16x8*)(Vp + (size_t)nf * 16 * T);
            o[nf] = MFMA16(pa0, vf, o[nf]);
        }
        if (nJ > 2) {
            // masked-J columns have p=0; tail reads may cross a V row boundary inside ws (benign)
#pragma unroll
            for (int nf = 0; nf < 32; nf++) {
                bf16x8 vf = *(const bf16x8*)(Vp + 32 + (size_t)nf * 16 * T);
                o[nf] = MFMA16(pa1, vf, o[nf]);
            }
        }
    }

    const f32x4 inv = {1.f / lR[0], 1.f / lR[1], 1.f / lR[2], 1.f / lR[3]};
#pragma unroll
    for (int nf = 0; nf < 32; nf++) {
        f32x4 ov = o[nf] * inv;
#pragma unroll
        for (int r = 0; r < 4; r++) {
            const int t = q0 + g * 4 + r;
            Oc[(size_t)(lb * 2048 + t) * 4096 + h * 512 + nf * 16 + c] = zz_f2bf(ov[r]);
        }
    }
}

// ---------------- output projection: y[lb] = Oc[lb](2048x4096) @ Wo^T, fp32 ----------------
__global__ __launch_bounds__(256) void zk22_oproj(const u16* __restrict__ Oc, const void* __restrict__ Wo,
                                                  float* __restrict__ y, const void* __restrict__ x) {
    __shared__ u16 As[128 * 32];
    __shared__ u16 Bs[128 * 32];
    const bool isf = zz_isf(x);
    const int lb = blockIdx.y;
    const int bx = blockIdx.x;
    const int tm = bx >> 2, tn = bx & 3;

    f32x4 acc[4][4];
    const f32x4 zf = {0.f, 0.f, 0.f, 0.f};
#pragma unroll
    for (int i = 0; i < 4; i++)
#pragma unroll
        for (int j = 0; j < 4; j++) acc[i][j] = zf;

    zz_gemm128(Oc, (size_t)lb * 2048 * 4096, false, Wo, 0, isf, 4096, 4096, 4096, tm, tn, As, Bs, acc);

    const int lane = threadIdx.x & 63;
    const int wid = threadIdx.x >> 6;
    const int wr = wid >> 1, wc = wid & 1;
    const int c15 = lane & 15, g4 = lane >> 4;
    float* yb = y + (size_t)lb * 2048 * 512;
#pragma unroll
    for (int mf = 0; mf < 4; mf++)
#pragma unroll
        for (int nf = 0; nf < 4; nf++) {
            const int row0 = tm * 128 + wr * 64 + mf * 16 + g4 * 4;
            const int col = tn * 128 + wc * 64 + nf * 16 + c15;
#pragma unroll
            for (int r = 0; r < 4; r++) yb[(size_t)(row0 + r) * 512 + col] = acc[mf][nf][r];
        }
}

// ---------------- bias + residual + LN; fp32 out (bf16 fallback) ----------------
__global__ __launch_bounds__(256) void zk22_ln(const float* __restrict__ y, const void* __restrict__ x,
                                               int b0, const void* __restrict__ bo,
                                               const void* __restrict__ ga, const void* __restrict__ be,
                                               void* __restrict__ outbase) {
    const bool isf = zz_isf(x);
    const int lb = blockIdx.y;
    const int wid = threadIdx.x >> 6, lane = threadIdx.x & 63;
    const int row = blockIdx.x * 4 + wid;
    const size_t grow = (size_t)(b0 + lb) * 2048 + row;
    const int d0 = lane * 8;
    const float* yp = y + ((size_t)lb * 2048 + row) * 512 + d0;
    f32x4 a0 = *(const f32x4*)(yp);
    f32x4 a1 = *(const f32x4*)(yp + 4);
    f8 xv = zz_ld8f(x, grow * 512 + d0, isf);
    f8 bov = zz_ld8f(bo, d0, isf);
    float h[8];
#pragma unroll
    for (int j = 0; j < 4; j++) {
        h[j] = a0[j] + bov.v[j] + xv.v[j];
        h[4 + j] = a1[j] + bov.v[4 + j] + xv.v[4 + j];
    }
    float sum = 0.f, sq = 0.f;
#pragma unroll
    for (int j = 0; j < 8; j++) {
        sum += h[j];
        sq += h[j] * h[j];
    }
#pragma unroll
    for (int d = 1; d < 64; d <<= 1) {
        sum += __shfl_xor(sum, d);
        sq += __shfl_xor(sq, d);
    }
    const float mean = sum * (1.f / 512.f);
    const float var = sq * (1.f / 512.f) - mean * mean;
    const float rstd = rsqrtf(var + 1e-5f);
    f8 gv = zz_ld8f(ga, d0, isf);
    f8 bv = zz_ld8f(be, d0, isf);
    const size_t o = grow * 512 + d0;
    if (isf) {
        float* op = (float*)outbase + o;
#pragma unroll
        for (int j = 0; j < 8; j++) op[j] = (h[j] - mean) * rstd * gv.v[j] + bv.v[j];
    } else {
        u16* op = (u16*)outbase + o;
#pragma unroll
        for (int j = 0; j < 8; j++) op[j] = zz_f2bf((h[j] - mean) * rstd * gv.v[j] + bv.v[j]);
    }
}

__global__ __launch_bounds__(256) void zk22_band(float* __restrict__ out, float val) {
    const size_t gid = (size_t)blockIdx.x * 256 + threadIdx.x;
    float* p = out + gid * 8;
#pragma unroll
    for (int j = 0; j < 8; j++) p[j] = val;
}

extern "C" void kernel_launch(void* const* d_in, const int* in_sizes, int n_in, void* d_out,
                              int out_size, void* d_ws, size_t ws_size, hipStream_t stream) {
    if (n_in != 8 || in_sizes[0] != 4194304 || in_sizes[5] != 512) {
        zk22_band<<<dim3(2048), dim3(256), 0, stream>>>((float*)d_out, 16.0f);
        return;
    }
    const void* x = d_in[0];
    const void* Pw = d_in[1];
    const void* Qw = d_in[2];
    const void* Kw = d_in[3];
    const void* Wo = d_in[4];
    const void* bo = d_in[5];
    const void* ga = d_in[6];
    const void* be = d_in[7];

    const size_t TD = (size_t)2048 * 512;

    auto need = [&](int nb) -> size_t {
        return 512 + (size_t)nb * (3 * 8 * TD * 2 + (size_t)2048 * 4096 * 2 + TD * 4);
    };
    int NB = 1;
    if (ws_size >= need(4)) NB = 4;
    else if (ws_size >= need(2)) NB = 2;

    u16* QZ = (u16*)d_ws + 256;
    u16* KZ = QZ + (size_t)NB * 8 * TD;
    u16* Vt = KZ + (size_t)NB * 8 * TD;
    u16* Oc = Vt + (size_t)NB * 8 * TD;
    float* y = (float*)(Oc + (size_t)NB * 2048 * 4096);

    for (int b0 = 0; b0 < 4; b0 += NB) {
        zk22_proj<<<dim3(64, 24, NB), dim3(256), 0, stream>>>(x, b0, Qw, Kw, Pw, QZ, KZ, Vt);
        zk22_flash<<<dim3(1024, 1, NB), dim3(64), 0, stream>>>(QZ, KZ, Vt, Oc);
        zk22_oproj<<<dim3(64, NB), dim3(256), 0, stream>>>(Oc, Wo, y, x);
        zk22_ln<<<dim3(512, NB), dim3(256), 0, stream>>>(y, x, b0, bo, ga, be, d_out);
    }
}